// Round 5
// baseline (73683.148 us; speedup 1.0000x reference)
//
#include <hip/hip_runtime.h>
#include <hip/hip_fp16.h>

// LSTM (S=16384, I=64, H=1024) -> ReLU -> FC(1024->128) -> ReLU -> FC(128->1), last step only.
// Persistent kernel, 64 blocks x 512 threads (8 waves). Wave w of block b owns h-columns
// 16b+2w, 16b+2w+1 (8 gate rows register-resident, PINNED via asm so the compiler cannot
// re-stream W_hh from L2 inside the step loop). Per-step device-wide h broadcast via
// self-validating (tag16, fp16) words, relaxed agent-scope atomics.
// Publish path has ZERO extra hops: every lane computes the activations (bit-identical),
// lane 0 issues one 8-B packed atomic store (single-copy atomic; consumers validate the
// matching u64 in one load). Poll is a 1-deep tight loop (no sleep): period ~ RTT.
// One __syncthreads per step (double-buffered h_stage). Own-block words bypass fabric.

#define S_LEN 16384
#define I_DIM 64
#define H_DIM 1024
#define NBLK  64
#define NTHR  512

__device__ __forceinline__ float sigmoidf_(float x) { return 1.0f / (1.0f + __expf(-x)); }
__device__ __forceinline__ float tanh_fast(float x) { return 1.0f - 2.0f / (__expf(2.0f * x) + 1.0f); }
__device__ __forceinline__ float unpack_val(unsigned pk) {
    return __half2float(__ushort_as_half((unsigned short)(pk & 0xFFFFu)));
}

__global__ __launch_bounds__(NTHR, 2) void lstm_persistent(
    const float* __restrict__ xseq,   // [S, 64]
    const float* __restrict__ W_ih,   // [4096, 64]
    const float* __restrict__ W_hh,   // [4096, 1024]
    const float* __restrict__ b_ih,   // [4096]
    const float* __restrict__ b_hh,   // [4096]
    unsigned* __restrict__ pairs)     // [2][1024] 4-B words (tag16<<16 | fp16 bits)
{
    const int b    = blockIdx.x;
    const int tid  = threadIdx.x;
    const int w    = tid >> 6;        // wave id 0..7 -> owns columns 16b+2w, 16b+2w+1
    const int c    = tid & 63;        // lane id
    const int colA = 16 * b + 2 * w;

    __shared__ float4 h_stage[2][H_DIM / 4];   // double-buffered h_{t-1} (fp16-rounded)

    // ---- one-time: weights into registers, PINNED (128 VGPRs of W_hh per thread) ----
    // Lane c covers h float4-chunks { m*64 + c : m=0..3 }. acc r: r<4 = gates i,f,g,o of
    // colA; r>=4 = gates of colB. The empty asm makes each loaded value opaque, so the
    // compiler must keep it in a VGPR instead of re-loading W_hh each iteration.
    float wh[8][16];
    float wi[8];
    float bsum[8];
    #pragma unroll
    for (int r = 0; r < 8; ++r) {
        const int col = colA + (r >> 2);
        const int q   = r & 3;
        const size_t row = (size_t)q * H_DIM + col;
        const float4* wr = (const float4*)(W_hh + row * H_DIM);
        #pragma unroll
        for (int m = 0; m < 4; ++m) {
            float4 v = wr[m * 64 + c];
            asm volatile("" : "+v"(v.x), "+v"(v.y), "+v"(v.z), "+v"(v.w));
            wh[r][4 * m + 0] = v.x; wh[r][4 * m + 1] = v.y;
            wh[r][4 * m + 2] = v.z; wh[r][4 * m + 3] = v.w;
        }
        wi[r]   = W_ih[row * I_DIM + c];
        bsum[r] = b_ih[row] + b_hh[row];
    }

    if (tid < H_DIM / 4) h_stage[0][tid] = make_float4(0.f, 0.f, 0.f, 0.f);  // h_{-1}=0
    float cstA = 0.f, cstB = 0.f;      // cell states (replicated, bit-identical per lane)
    float xv = xseq[c];                // x_0
    // thread tid polls words 2*tid, 2*tid+1; own-block words [16b,16b+16) <=> tid in [8b,8b+8)
    const bool own = (tid >= 8 * b) && (tid < 8 * b + 8);
    __syncthreads();

    for (int t = 0; t < S_LEN; ++t) {
        const int cur = t & 1, nxt = cur ^ 1;
        const unsigned tag = (unsigned)(t + 1);

        // ---- gates: W_hh . h_{t-1} + W_ih . x_t (4 ds_read_b128 + 128 FMA + 8 FMA) ----
        float acc[8];
        #pragma unroll
        for (int r = 0; r < 8; ++r) acc[r] = wi[r] * xv;
        #pragma unroll
        for (int m = 0; m < 4; ++m) {
            const float4 hv = h_stage[cur][m * 64 + c];
            #pragma unroll
            for (int r = 0; r < 8; ++r) {
                acc[r] = fmaf(wh[r][4 * m + 0], hv.x, acc[r]);
                acc[r] = fmaf(wh[r][4 * m + 1], hv.y, acc[r]);
                acc[r] = fmaf(wh[r][4 * m + 2], hv.z, acc[r]);
                acc[r] = fmaf(wh[r][4 * m + 3], hv.w, acc[r]);
            }
        }

        // prefetch x_{t+1} (independent; hides under the shuffle chain; cache-hot line)
        if (t + 1 < S_LEN) xv = xseq[(size_t)(t + 1) * I_DIM + c];

        // ---- full-wave butterfly reduction (all lanes end bit-identical) ----
        #pragma unroll
        for (int off = 32; off > 0; off >>= 1) {
            #pragma unroll
            for (int r = 0; r < 8; ++r) acc[r] += __shfl_xor(acc[r], off, 64);
        }

        // ---- activations + state update on all lanes (divergence-free) ----
        const float igA = sigmoidf_(acc[0] + bsum[0]);
        const float fgA = sigmoidf_(acc[1] + bsum[1]);
        const float ggA = tanh_fast (acc[2] + bsum[2]);
        const float ogA = sigmoidf_(acc[3] + bsum[3]);
        cstA = fgA * cstA + igA * ggA;
        const float hA = ogA * tanh_fast(cstA);
        const float igB = sigmoidf_(acc[4] + bsum[4]);
        const float fgB = sigmoidf_(acc[5] + bsum[5]);
        const float ggB = tanh_fast (acc[6] + bsum[6]);
        const float ogB = sigmoidf_(acc[7] + bsum[7]);
        cstB = fgB * cstB + igB * ggB;
        const float hB = ogB * tanh_fast(cstB);

        // ---- publish directly: ONE 8-B packed atomic store from lane 0 (no hops) ----
        const unsigned pkA = (tag << 16) | (unsigned)__half_as_ushort(__float2half(hA));
        const unsigned pkB = (tag << 16) | (unsigned)__half_as_ushort(__float2half(hB));
        if (c == 0) {
            const unsigned long long both = ((unsigned long long)pkB << 32) | pkA;
            __hip_atomic_store(
                (unsigned long long*)&pairs[(size_t)cur * H_DIM + colA], both,
                __ATOMIC_RELAXED, __HIP_MEMORY_SCOPE_AGENT);
            // own-columns LDS bypass: same fp16-rounded values remote blocks will see
            ((float2*)h_stage[nxt])[8 * b + w] =
                make_float2(unpack_val(pkA), unpack_val(pkB));
        }

        if (t == S_LEN - 1) break;   // last h published; nothing left to read

        // ---- poll: 1-deep tight loop, one 8-B tagged load covers words 2*tid,2*tid+1 ----
        if (!own) {
            const unsigned long long tag2 =
                ((unsigned long long)tag << 48) | ((unsigned long long)tag << 16);
            const unsigned long long* p =
                (const unsigned long long*)&pairs[(size_t)cur * H_DIM + 2 * tid];
            unsigned long long v;
            for (;;) {
                v = __hip_atomic_load(p, __ATOMIC_RELAXED, __HIP_MEMORY_SCOPE_AGENT);
                if (((v ^ tag2) & 0xFFFF0000FFFF0000ull) == 0ull) break;
            }
            ((float2*)h_stage[nxt])[tid] =
                make_float2(unpack_val((unsigned)v), unpack_val((unsigned)(v >> 32)));
        }
        __syncthreads();   // the single per-step barrier: h_stage[nxt] complete
    }
}

// Final head: out = fc2( relu( fc1( relu(h_{S-1}) ) ) ). h_{S-1} is in pairs
// slot 1 ((S-1)&1). Kernel-boundary ordering makes plain loads safe.
__global__ __launch_bounds__(256) void fc_head(
    const unsigned* __restrict__ pairs,
    const float* __restrict__ fc1_w,  // [128, 1024]
    const float* __restrict__ fc1_b,  // [128]
    const float* __restrict__ fc2_w,  // [128]
    const float* __restrict__ fc2_b,  // [1]
    float* __restrict__ out)
{
    const int tid = threadIdx.x;
    __shared__ float4 hr4[H_DIM / 4];
    __shared__ float  partial[256];
    __shared__ float  r1[128];

    // extract fp16 h values from slot-1 pairs (4 pairs per thread)
    const uint4 pa = ((const uint4*)(pairs + H_DIM))[tid];
    float4 hv = make_float4(__half2float(__ushort_as_half((unsigned short)(pa.x & 0xFFFFu))),
                            __half2float(__ushort_as_half((unsigned short)(pa.y & 0xFFFFu))),
                            __half2float(__ushort_as_half((unsigned short)(pa.z & 0xFFFFu))),
                            __half2float(__ushort_as_half((unsigned short)(pa.w & 0xFFFFu))));
    hv.x = fmaxf(hv.x, 0.f); hv.y = fmaxf(hv.y, 0.f);
    hv.z = fmaxf(hv.z, 0.f); hv.w = fmaxf(hv.w, 0.f);
    hr4[tid] = hv;
    __syncthreads();

    const int row = tid & 127, half = tid >> 7;
    const float4* wrow = (const float4*)(fc1_w + (size_t)row * H_DIM) + half * 128;
    float a0 = 0.f, a1 = 0.f;
    #pragma unroll 4
    for (int i = 0; i < 128; i += 2) {
        const float4 w0 = wrow[i],     h0 = hr4[half * 128 + i];
        const float4 w1 = wrow[i + 1], h1 = hr4[half * 128 + i + 1];
        a0 += w0.x * h0.x + w0.y * h0.y + w0.z * h0.z + w0.w * h0.w;
        a1 += w1.x * h1.x + w1.y * h1.y + w1.z * h1.z + w1.w * h1.w;
    }
    partial[tid] = a0 + a1;
    __syncthreads();
    if (tid < 128) {
        const float s = partial[tid] + partial[tid + 128] + fc1_b[tid];
        r1[tid] = fmaxf(s, 0.f);
    }
    __syncthreads();
    if (tid < 64) {
        float v = r1[tid] * fc2_w[tid] + r1[tid + 64] * fc2_w[tid + 64];
        #pragma unroll
        for (int off = 32; off > 0; off >>= 1) v += __shfl_xor(v, off, 64);
        if (tid == 0) out[0] = v + fc2_b[0];
    }
}

extern "C" void kernel_launch(void* const* d_in, const int* in_sizes, int n_in,
                              void* d_out, int out_size, void* d_ws, size_t ws_size,
                              hipStream_t stream) {
    (void)in_sizes; (void)n_in; (void)out_size; (void)ws_size;
    const float* xseq  = (const float*)d_in[0];
    const float* W_ih  = (const float*)d_in[1];
    const float* W_hh  = (const float*)d_in[2];
    const float* b_ih  = (const float*)d_in[3];
    const float* b_hh  = (const float*)d_in[4];
    const float* fc1_w = (const float*)d_in[5];
    const float* fc1_b = (const float*)d_in[6];
    const float* fc2_w = (const float*)d_in[7];
    const float* fc2_b = (const float*)d_in[8];
    unsigned* pairs = (unsigned*)d_ws;

    lstm_persistent<<<NBLK, NTHR, 0, stream>>>(xseq, W_ih, W_hh, b_ih, b_hh, pairs);
    fc_head<<<1, 256, 0, stream>>>(pairs, fc1_w, fc1_b, fc2_w, fc2_b, (float*)d_out);
}

// Round 6
// 40098.611 us; speedup vs baseline: 1.8375x; 1.8375x over previous
//
#include <hip/hip_runtime.h>
#include <hip/hip_fp16.h>

// LSTM (S=16384, I=64, H=1024) -> ReLU -> FC(1024->128) -> ReLU -> FC(128->1), last step only.
// Persistent kernel, 64 blocks x 1024 threads (16 waves). Wave w of block b owns h-column
// 16b+w (ALL 4 gates -> 4 rows, 64 FMA/lane, same op count as baseline). Per-step
// device-wide h broadcast via self-validating (tag16, fp16) words, relaxed agent-scope
// atomics. Activation runs IN-WAVE on all lanes (bit-identical, before barrier-A) --
// removing the baseline's post-barrier serialized activation + gs round trip from the
// serial path. Lane 0 posts the packed word to an LDS mailbox; after barrier-A wave 0
// reads it (no spin; barrier guarantees freshness) and issues the block's ONE coalesced
// 64-B line store (16 x 4-B from lanes 0..15 -- proven essential fabric discipline).
// Poll: s_sleep(1)-throttled 4-B tagged load per thread (the proven pattern; polls are
// L2-served, ~1 LLC refill per line per XCD per step). Two barriers per step as baseline.

#define S_LEN 16384
#define I_DIM 64
#define H_DIM 1024
#define NBLK  64
#define NTHR  1024

__device__ __forceinline__ float sigmoidf_(float x) { return 1.0f / (1.0f + __expf(-x)); }
__device__ __forceinline__ float tanh_fast(float x) { return 1.0f - 2.0f / (__expf(2.0f * x) + 1.0f); }
__device__ __forceinline__ float unpack_val(unsigned pk) {
    return __half2float(__ushort_as_half((unsigned short)(pk & 0xFFFFu)));
}

__global__ __launch_bounds__(NTHR, 4) void lstm_persistent(
    const float* __restrict__ xseq,   // [S, 64]
    const float* __restrict__ W_ih,   // [4096, 64]
    const float* __restrict__ W_hh,   // [4096, 1024]
    const float* __restrict__ b_ih,   // [4096]
    const float* __restrict__ b_hh,   // [4096]
    unsigned* __restrict__ pairs)     // [2][1024] 4-B words (tag16<<16 | fp16 bits)
{
    const int b   = blockIdx.x;
    const int tid = threadIdx.x;
    const int w   = tid >> 6;        // wave id 0..15 -> owns column 16b+w, all 4 gates
    const int c   = tid & 63;        // lane id
    const int col = 16 * b + w;

    __shared__ float4   h_stage[H_DIM / 4];   // h_{t-1} (fp16-rounded fp32)
    __shared__ float    x_stage[2][I_DIM];
    __shared__ unsigned pub[16];              // per-wave packed h word (mailbox)

    // ---- one-time: weights into registers (coalesced float4 loads) ----
    // Lane c covers h float4-chunks { m*64 + c : m=0..3 }; wh[q] = gate q's row of col.
    float4 wh[4][4];
    float  wi[4];
    float  bsum[4];
    #pragma unroll
    for (int q = 0; q < 4; ++q) {
        const size_t row = (size_t)q * H_DIM + col;
        const float4* wr = (const float4*)(W_hh + row * H_DIM);
        #pragma unroll
        for (int m = 0; m < 4; ++m) wh[q][m] = wr[m * 64 + c];
        wi[q]   = W_ih[row * I_DIM + c];
        bsum[q] = b_ih[row] + b_hh[row];     // wave-uniform -> scalar regs
    }

    if (tid < H_DIM / 4) h_stage[tid] = make_float4(0.f, 0.f, 0.f, 0.f);  // h_{-1}=0
    if (tid < 16) ((float4*)x_stage[0])[tid] = ((const float4*)xseq)[tid];
    const bool own = (tid >> 4) == b;    // word `tid` is produced by this block
    float cst = 0.0f;                    // cell state (replicated, bit-identical per lane)
    __syncthreads();

    for (int t = 0; t < S_LEN; ++t) {
        // prefetch x_{t+1} into the other parity slot (no serial dependency)
        if (tid < 16 && t + 1 < S_LEN)
            ((float4*)x_stage[(t + 1) & 1])[tid] =
                ((const float4*)(xseq + (size_t)(t + 1) * I_DIM))[tid];

        // ---- gates: W_hh . h_{t-1} + W_ih . x_t (4 ds_read_b128 + 64 FMA + 4 FMA) ----
        const float xv = x_stage[t & 1][c];
        float acc0 = wi[0] * xv, acc1 = wi[1] * xv, acc2 = wi[2] * xv, acc3 = wi[3] * xv;
        #pragma unroll
        for (int m = 0; m < 4; ++m) {
            const float4 hv = h_stage[m * 64 + c];
            acc0 = fmaf(wh[0][m].x, hv.x, acc0); acc0 = fmaf(wh[0][m].y, hv.y, acc0);
            acc0 = fmaf(wh[0][m].z, hv.z, acc0); acc0 = fmaf(wh[0][m].w, hv.w, acc0);
            acc1 = fmaf(wh[1][m].x, hv.x, acc1); acc1 = fmaf(wh[1][m].y, hv.y, acc1);
            acc1 = fmaf(wh[1][m].z, hv.z, acc1); acc1 = fmaf(wh[1][m].w, hv.w, acc1);
            acc2 = fmaf(wh[2][m].x, hv.x, acc2); acc2 = fmaf(wh[2][m].y, hv.y, acc2);
            acc2 = fmaf(wh[2][m].z, hv.z, acc2); acc2 = fmaf(wh[2][m].w, hv.w, acc2);
            acc3 = fmaf(wh[3][m].x, hv.x, acc3); acc3 = fmaf(wh[3][m].y, hv.y, acc3);
            acc3 = fmaf(wh[3][m].z, hv.z, acc3); acc3 = fmaf(wh[3][m].w, hv.w, acc3);
        }

        // ---- full-wave butterfly reduction (all lanes end bit-identical) ----
        #pragma unroll
        for (int off = 32; off > 0; off >>= 1) {
            acc0 += __shfl_xor(acc0, off, 64);
            acc1 += __shfl_xor(acc1, off, 64);
            acc2 += __shfl_xor(acc2, off, 64);
            acc3 += __shfl_xor(acc3, off, 64);
        }

        // ---- in-wave activation on all lanes (divergence-free, BEFORE barrier-A) ----
        const float ig = sigmoidf_(acc0 + bsum[0]);
        const float fg = sigmoidf_(acc1 + bsum[1]);
        const float gg = tanh_fast (acc2 + bsum[2]);
        const float og = sigmoidf_(acc3 + bsum[3]);
        cst = fg * cst + ig * gg;
        const float h = og * tanh_fast(cst);
        const unsigned pkv = ((unsigned)(t + 1) << 16) |
                             (unsigned)__half_as_ushort(__float2half(h));
        if (c == 0) pub[w] = pkv;     // plain LDS store; barrier-A publishes it

        __syncthreads();   // barrier A: pub[] visible; all h_stage reads of step t done

        // ---- wave 0: gather mailbox (no spin), ONE coalesced 64-B line store ----
        if (w == 0 && c < 16) {
            const unsigned pk = pub[c];
            __hip_atomic_store(&pairs[(size_t)(t & 1) * H_DIM + 16 * b + c], pk,
                               __ATOMIC_RELAXED, __HIP_MEMORY_SCOPE_AGENT);
            // own-block bypass: same fp16-rounded values remote blocks will see
            ((float*)h_stage)[16 * b + c] = unpack_val(pk);
        }

        if (t == S_LEN - 1) break;   // last h published; nothing left to read

        // ---- poll word `tid` (tag+data in one 4-B load), s_sleep(1)-throttled ----
        if (!own) {
            const unsigned tag = (unsigned)(t + 1);
            const unsigned* p = &pairs[(size_t)(t & 1) * H_DIM + tid];
            unsigned pk;
            for (;;) {
                pk = __hip_atomic_load(p, __ATOMIC_RELAXED, __HIP_MEMORY_SCOPE_AGENT);
                if ((pk >> 16) == tag) break;
                __builtin_amdgcn_s_sleep(1);
            }
            ((float*)h_stage)[tid] = unpack_val(pk);
        }
        __syncthreads();   // barrier B: h_stage fully updated to h_t
    }
}

// Final head: out = fc2( relu( fc1( relu(h_{S-1}) ) ) ). h_{S-1} is in pairs
// slot 1 ((S-1)&1). Kernel-boundary ordering makes plain loads safe.
__global__ __launch_bounds__(256) void fc_head(
    const unsigned* __restrict__ pairs,
    const float* __restrict__ fc1_w,  // [128, 1024]
    const float* __restrict__ fc1_b,  // [128]
    const float* __restrict__ fc2_w,  // [128]
    const float* __restrict__ fc2_b,  // [1]
    float* __restrict__ out)
{
    const int tid = threadIdx.x;
    __shared__ float4 hr4[H_DIM / 4];
    __shared__ float  partial[256];
    __shared__ float  r1[128];

    // extract fp16 h values from slot-1 pairs (4 pairs per thread)
    const uint4 pa = ((const uint4*)(pairs + H_DIM))[tid];
    float4 hv = make_float4(__half2float(__ushort_as_half((unsigned short)(pa.x & 0xFFFFu))),
                            __half2float(__ushort_as_half((unsigned short)(pa.y & 0xFFFFu))),
                            __half2float(__ushort_as_half((unsigned short)(pa.z & 0xFFFFu))),
                            __half2float(__ushort_as_half((unsigned short)(pa.w & 0xFFFFu))));
    hv.x = fmaxf(hv.x, 0.f); hv.y = fmaxf(hv.y, 0.f);
    hv.z = fmaxf(hv.z, 0.f); hv.w = fmaxf(hv.w, 0.f);
    hr4[tid] = hv;
    __syncthreads();

    const int row = tid & 127, half = tid >> 7;
    const float4* wrow = (const float4*)(fc1_w + (size_t)row * H_DIM) + half * 128;
    float a0 = 0.f, a1 = 0.f;
    #pragma unroll 4
    for (int i = 0; i < 128; i += 2) {
        const float4 w0 = wrow[i],     h0 = hr4[half * 128 + i];
        const float4 w1 = wrow[i + 1], h1 = hr4[half * 128 + i + 1];
        a0 += w0.x * h0.x + w0.y * h0.y + w0.z * h0.z + w0.w * h0.w;
        a1 += w1.x * h1.x + w1.y * h1.y + w1.z * h1.z + w1.w * h1.w;
    }
    partial[tid] = a0 + a1;
    __syncthreads();
    if (tid < 128) {
        const float s = partial[tid] + partial[tid + 128] + fc1_b[tid];
        r1[tid] = fmaxf(s, 0.f);
    }
    __syncthreads();
    if (tid < 64) {
        float v = r1[tid] * fc2_w[tid] + r1[tid + 64] * fc2_w[tid + 64];
        #pragma unroll
        for (int off = 32; off > 0; off >>= 1) v += __shfl_xor(v, off, 64);
        if (tid == 0) out[0] = v + fc2_b[0];
    }
}

extern "C" void kernel_launch(void* const* d_in, const int* in_sizes, int n_in,
                              void* d_out, int out_size, void* d_ws, size_t ws_size,
                              hipStream_t stream) {
    (void)in_sizes; (void)n_in; (void)out_size; (void)ws_size;
    const float* xseq  = (const float*)d_in[0];
    const float* W_ih  = (const float*)d_in[1];
    const float* W_hh  = (const float*)d_in[2];
    const float* b_ih  = (const float*)d_in[3];
    const float* b_hh  = (const float*)d_in[4];
    const float* fc1_w = (const float*)d_in[5];
    const float* fc1_b = (const float*)d_in[6];
    const float* fc2_w = (const float*)d_in[7];
    const float* fc2_b = (const float*)d_in[8];
    unsigned* pairs = (unsigned*)d_ws;

    lstm_persistent<<<NBLK, NTHR, 0, stream>>>(xseq, W_ih, W_hh, b_ih, b_hh, pairs);
    fc_head<<<1, 256, 0, stream>>>(pairs, fc1_w, fc1_b, fc2_w, fc2_b, (float*)d_out);
}